// Round 3
// baseline (690.076 us; speedup 1.0000x reference)
//
#include <hip/hip_runtime.h>

// Problem constants
#define N_    8
#define TP_   2048
#define E_    4096
#define S_    8
#define C_    64
#define T_    16384      // TP_*S_
#define TS_   131072     // T_*S_
#define OUTW  17         // V+1
#define OUT_ELEMS 17825792  // N_*TS_*OUTW
#define F4_PER_N 557056     // 16384 rows * 34 float4 per row
#define F4_TOTAL 4456448    // OUT_ELEMS/4

typedef __attribute__((ext_vector_type(8))) short short8;
typedef __attribute__((ext_vector_type(4))) float float4v;

static __device__ __forceinline__ unsigned short f2bf(float f) {
    unsigned int u = __builtin_bit_cast(unsigned int, f);
    u += 0x7FFFu + ((u >> 16) & 1u);   // round-to-nearest-even
    return (unsigned short)(u >> 16);
}

// ---------------------------------------------------------------------------
// prep: LDS-tiled transpose W1 [4096][512] fp32 -> Bb [512][4096] bf16
//   Bb row index = c*8+s (natural W1 inner order); main indexes rows as c*8+s.
//   Block (0,0) also computes K2[s2] = b2 + sum_c b1[c]*W2[c,0,s2].
// ---------------------------------------------------------------------------
__global__ __launch_bounds__(256) void prep_kernel(
    const float* __restrict__ W1, const float* __restrict__ b1,
    const float* __restrict__ W2, const float* __restrict__ b2,
    unsigned short* __restrict__ Bb, float* __restrict__ K2)
{
    __shared__ float tile[64][65];
    const int tid = threadIdx.x;
    if (blockIdx.x == 0 && blockIdx.y == 0 && tid < 8) {
        int s2 = tid;
        float acc = b2[0];
        for (int c = 0; c < C_; ++c) acc += b1[c] * W2[c * S_ + s2];
        K2[s2] = acc;
    }
    const int e0  = blockIdx.x * 64;   // 64 e-tiles
    const int cs0 = blockIdx.y * 64;   // 8 cs-tiles
    {
        int rr = tid >> 2;        // e row 0..63
        int c4 = tid & 3;
        for (int i = 0; i < 4; ++i) {
            int f4 = c4 + i * 4;  // 0..15
            float4 v = *(const float4*)&W1[(size_t)(e0 + rr) * 512 + cs0 + f4 * 4];
            tile[f4 * 4 + 0][rr] = v.x;
            tile[f4 * 4 + 1][rr] = v.y;
            tile[f4 * 4 + 2][rr] = v.z;
            tile[f4 * 4 + 3][rr] = v.w;
        }
    }
    __syncthreads();
    {
        int cs  = tid >> 2;       // 0..63
        int seg = tid & 3;        // 16 shorts each
        for (int h = 0; h < 2; ++h) {
            short8 o;
#pragma unroll
            for (int j = 0; j < 8; ++j)
                o[j] = (short)f2bf(tile[cs][seg * 16 + h * 8 + j]);
            *(short8*)&Bb[(size_t)(cs0 + cs) * E_ + e0 + seg * 16 + h * 8] = o;
        }
    }
}

// ---------------------------------------------------------------------------
// compact: per (n,s) block; int4 value loads; wave-shuffle scan; 64-ary
// argmax search; builds gathered row lists + global tile work-list.
// ---------------------------------------------------------------------------
__global__ __launch_bounds__(256) void compact_kernel(
    const int* __restrict__ value, const int* __restrict__ depth,
    int* __restrict__ cnt_ns, int* __restrict__ cnt_total,
    int* __restrict__ tile_counter, int* __restrict__ tiles,
    int* __restrict__ sel_tp, int* __restrict__ sel_j)
{
    const int g = blockIdx.x;          // n*8 + s
    const int n = g >> 3;
    const int s = g & 7;
    const int tid  = threadIdx.x;
    const int lane = tid & 63;
    const int wv   = tid >> 6;

    __shared__ int idx_sh;
    __shared__ unsigned int wsum[4];

    const int* d = depth + (size_t)n * T_;
    if (tid < 64) {                    // wave 0: 64-ary search, 3 rounds
        int maxv = d[T_ - 1];
        int lower = 0, upper = T_ - 1;
        for (int rnd = 0; rnd < 3; ++rnd) {
            int span = upper - lower;
            int step = (span + 63) >> 6;
            if (step < 1) step = 1;
            int p = lower + lane * step;
            if (p > upper) p = upper;
            unsigned long long b = __ballot(d[p] == maxv);
            int f = __ffsll((long long)b) - 1;   // ballot never 0: d[upper]==maxv
            int nu = lower + f * step; if (nu > upper) nu = upper;
            int nl = (f == 0) ? lower : lower + (f - 1) * step + 1;
            if (nl > nu) nl = nu;
            lower = nl; upper = nu;
        }
        if (lane == 0) idx_sh = lower;
    }
    __syncthreads();
    const int idx = idx_sh;
    const int4* val4 = (const int4*)(value + (size_t)n * T_);

    const int b4 = tid * 16;           // int4 index base; covers t in [tid*64, tid*64+64)
    unsigned int packed = 0;           // (any-count << 16) | s-residue count
    for (int i = 0; i < 16; ++i) {
        int4 v = val4[b4 + i];
        int t = (b4 + i) * 4;
        if (t + 0 < idx && v.x == 2) { packed += 0x10000u; if (((t + 0) & 7) == s) packed += 1u; }
        if (t + 1 < idx && v.y == 2) { packed += 0x10000u; if (((t + 1) & 7) == s) packed += 1u; }
        if (t + 2 < idx && v.z == 2) { packed += 0x10000u; if (((t + 2) & 7) == s) packed += 1u; }
        if (t + 3 < idx && v.w == 2) { packed += 0x10000u; if (((t + 3) & 7) == s) packed += 1u; }
    }
    unsigned int inc = packed;
#pragma unroll
    for (int off = 1; off < 64; off <<= 1) {
        unsigned int u = __shfl_up((int)inc, off, 64);
        if (lane >= off) inc += u;
    }
    if (lane == 63) wsum[wv] = inc;
    __syncthreads();
    unsigned int woff = 0;
    for (int ww = 0; ww < wv; ++ww) woff += wsum[ww];
    unsigned int excl = woff + inc - packed;
    int any_rank = (int)(excl >> 16);
    int s_rank   = (int)(excl & 0xFFFFu);
    for (int i = 0; i < 16; ++i) {
        int4 v = val4[b4 + i];
        int vv[4] = { v.x, v.y, v.z, v.w };
        int t = (b4 + i) * 4;
#pragma unroll
        for (int e = 0; e < 4; ++e) {
            int tt = t + e;
            if (tt < idx && vv[e] == 2) {
                if ((tt & 7) == s) {
                    sel_tp[g * 2048 + s_rank] = tt >> 3;
                    sel_j [g * 2048 + s_rank] = any_rank;
                    ++s_rank;
                }
                ++any_rank;
            }
        }
    }
    if (tid == 255) {
        unsigned int tot = woff + inc;
        int cnt = (int)(tot & 0xFFFFu);
        cnt_ns[g] = cnt;
        if (s == 0) cnt_total[n] = (int)(tot >> 16);
        int ntl = (cnt + 63) >> 6;
        int base = atomicAdd(tile_counter, ntl);
        for (int i = 0; i < ntl; ++i) tiles[base + i] = (g << 8) | i;
    }
}

// ---------------------------------------------------------------------------
// fill: vectorized b2*W3 pattern; skips rows j < cnt_total[n] (main overwrites)
// ---------------------------------------------------------------------------
__global__ __launch_bounds__(256) void fill_kernel(
    float* __restrict__ out, const float* __restrict__ W3,
    const float* __restrict__ b2, const int* __restrict__ cnt_total)
{
    __shared__ float pat[136];
    const int tid = threadIdx.x;
    if (tid < 136) pat[tid] = b2[0] * W3[tid % OUTW];
    __syncthreads();
    int i4 = blockIdx.x * 256 + tid;          // < F4_TOTAL exactly
    int n   = i4 / F4_PER_N;
    int rem = i4 - n * F4_PER_N;
    int j   = rem / 34;                       // output row within sample
    if (j >= cnt_total[n]) {
        int o = (rem - j * 34) * 4;
        float4 v = { pat[o], pat[o + 1], pat[o + 2], pat[o + 3] };
        *(float4*)&out[(size_t)i4 * 4] = v;
    }
}

// ---------------------------------------------------------------------------
// main: work-list driven gathered bf16 MFMA GEMM (64 rows x 64 ch, K=4096),
// 2-deep register prefetch + LDS double buffer (1 barrier/iter),
// fused conv2/linear epilogue with coalesced float4 writes.
// ---------------------------------------------------------------------------
__global__ __launch_bounds__(256) void main_kernel(
    const float* __restrict__ x, const unsigned short* __restrict__ Bb,
    const int* __restrict__ tile_counter, const int* __restrict__ tiles,
    const int* __restrict__ cnt_ns, const int* __restrict__ sel_tp,
    const int* __restrict__ sel_j, const float* __restrict__ K2,
    const float* __restrict__ W2, const float* __restrict__ W3,
    float* __restrict__ out)
{
    __shared__ __align__(16) char arena[36864];  // bufA[2]+bufB[2] ∪ (Cl + y2s)
    unsigned short (*bufA)[64][72] = (unsigned short (*)[64][72])arena;
    unsigned short (*bufB)[64][72] = (unsigned short (*)[64][72])(arena + 18432);
    float (*Cl)[68] = (float (*)[68])arena;       // 64x68 fp32 = 17408 B
    float (*y2s)[8] = (float (*)[8])(arena + 17408);  // 64x8 fp32 = 2048 B
    __shared__ int tp_l[64], j_l[64];
    __shared__ float W2s[C_ * S_];
    __shared__ float W3s[OUTW];
    __shared__ float K2s[S_];

    const int tid = threadIdx.x;
    for (int i = tid; i < C_ * S_; i += 256) W2s[i] = W2[i];
    if (tid < OUTW) W3s[tid] = W3[tid];
    if (tid < S_)   K2s[tid] = K2[tid];

    const int ntile = *tile_counter;

    const int lane = tid & 63;
    const int w    = tid >> 6;        // wave id: A rows [w*16, w*16+16)
    const int m    = lane & 15;
    const int q    = lane >> 4;
    const int r    = tid >> 4;        // staging row 0..15
    const int kq   = (tid & 15) << 2; // staging k-offset 0..60

    for (int ti = blockIdx.x; ti < ntile; ti += gridDim.x) {
        const int ent = tiles[ti];
        const int g = ent >> 8;
        const int n = g >> 3;
        const int s = g & 7;
        const int m0 = (ent & 255) * 64;
        const int rows = min(64, cnt_ns[g] - m0);

        __syncthreads();   // previous tile's epilogue fully done (LDS reuse)
        if (tid < 64) {
            int tp = 0, j = 0;
            if (tid < rows) {
                tp = sel_tp[g * 2048 + m0 + tid];
                j  = sel_j [g * 2048 + m0 + tid];
            }
            tp_l[tid] = tp;
            j_l[tid]  = j;
        }
        __syncthreads();

        const float* ap[4];
        const unsigned short* bp[4];
#pragma unroll
        for (int l = 0; l < 4; ++l) {
            int row = r + (l << 4);
            ap[l] = x + ((size_t)n * TP_ + tp_l[row]) * E_ + kq;
            bp[l] = Bb + ((size_t)(row * 8 + s)) * E_ + kq;   // Bb row = c*8+s
        }

        // 2-deep register prefetch: set p holds k-chunk with parity p
        float4  Af[2][4];
        ushort4 Bf[2][4];
#pragma unroll
        for (int pp = 0; pp < 2; ++pp)
#pragma unroll
            for (int l = 0; l < 4; ++l) {
                Af[pp][l] = *(const float4*)(ap[l] + pp * 64);
                Bf[pp][l] = *(const ushort4*)(bp[l] + pp * 64);
            }

        float4v acc[4];
#pragma unroll
        for (int nt = 0; nt < 4; ++nt) acc[nt] = (float4v){0.f, 0.f, 0.f, 0.f};

        for (int kb = 0; kb < 64; ++kb) {
            const int p = kb & 1;
#pragma unroll
            for (int l = 0; l < 4; ++l) {
                int row = r + (l << 4);
                ushort4 av;
                av.x = f2bf(Af[p][l].x); av.y = f2bf(Af[p][l].y);
                av.z = f2bf(Af[p][l].z); av.w = f2bf(Af[p][l].w);
                *(ushort4*)&bufA[p][row][kq] = av;
                *(ushort4*)&bufB[p][row][kq] = Bf[p][l];
            }
            __syncthreads();
            if (kb < 62) {            // refill set p for iteration kb+2
                const int k0 = (kb + 2) * 64;
#pragma unroll
                for (int l = 0; l < 4; ++l) {
                    Af[p][l] = *(const float4*)(ap[l] + k0);
                    Bf[p][l] = *(const ushort4*)(bp[l] + k0);
                }
            }
#pragma unroll
            for (int ks = 0; ks < 2; ++ks) {
                short8 a = *(const short8*)&bufA[p][w * 16 + m][ks * 32 + q * 8];
#pragma unroll
                for (int nt = 0; nt < 4; ++nt) {
                    short8 b = *(const short8*)&bufB[p][nt * 16 + m][ks * 32 + q * 8];
                    acc[nt] = __builtin_amdgcn_mfma_f32_16x16x32_bf16(a, b, acc[nt], 0, 0, 0);
                }
            }
        }
        __syncthreads();   // all LDS reads done before Cl alias write

        // D layout: row = q*4+reg, col = lane&15 (m89-verified)
#pragma unroll
        for (int nt = 0; nt < 4; ++nt)
#pragma unroll
            for (int rr = 0; rr < 4; ++rr)
                Cl[w * 16 + q * 4 + rr][nt * 16 + m] = acc[nt][rr];
        __syncthreads();

        // y2[row][s2] = K2[s2] + sum_c C[row][c]*W2[c,s2]
        for (int task = tid; task < 512; task += 256) {
            int row = task >> 3;
            int s2  = task & 7;
            float y2 = K2s[s2];
#pragma unroll
            for (int c = 0; c < C_; ++c) y2 += Cl[row][c] * W2s[c * S_ + s2];
            y2s[row][s2] = y2;
        }
        __syncthreads();

        // coalesced writes: each output row is 136 consecutive floats = 34 f4
        for (int task = tid; task < 64 * 34; task += 256) {
            int row = task / 34;
            int f   = task - row * 34;
            if (row < rows) {
                float4 v;
                float* vp = (float*)&v;
#pragma unroll
                for (int e = 0; e < 4; ++e) {
                    int idx = f * 4 + e;
                    int s2  = (idx * 241) >> 12;   // idx/17 for idx<136
                    int vi  = idx - s2 * OUTW;
                    vp[e] = y2s[row][s2] * W3s[vi];
                }
                *(float4*)&out[((size_t)n * TS_ + (size_t)j_l[row] * S_) * OUTW + f * 4] = v;
            }
        }
    }
}

// ---------------------------------------------------------------------------
extern "C" void kernel_launch(void* const* d_in, const int* in_sizes, int n_in,
                              void* d_out, int out_size, void* d_ws, size_t ws_size,
                              hipStream_t stream) {
    const float* x     = (const float*)d_in[0];
    const int*   value = (const int*)d_in[1];
    const int*   depth = (const int*)d_in[2];
    // d_in[3] = pos (unused by reference)
    const float* W1    = (const float*)d_in[4];
    const float* b1    = (const float*)d_in[5];
    const float* W2    = (const float*)d_in[6];
    const float* b2    = (const float*)d_in[7];
    const float* W3    = (const float*)d_in[8];
    float* out = (float*)d_out;

    // workspace layout (~5.25 MB)
    unsigned short* Bb = (unsigned short*)d_ws;            // 512*4096 bf16 = 4 MB
    float* K2          = (float*)(Bb + 512 * 4096);        // 8
    int* tile_counter  = (int*)(K2 + 8);                   // 1
    int* cnt_ns        = tile_counter + 1;                 // 64
    int* cnt_total     = cnt_ns + 64;                      // 8
    int* tiles         = cnt_total + 8;                    // 2048 max
    int* sel_tp        = tiles + 2048;                     // 64*2048
    int* sel_j         = sel_tp + 64 * 2048;               // 64*2048

    hipMemsetAsync(tile_counter, 0, sizeof(int), stream);

    dim3 pgrid(64, 8);
    prep_kernel<<<pgrid, 256, 0, stream>>>(W1, b1, W2, b2, Bb, K2);
    compact_kernel<<<64, 256, 0, stream>>>(value, depth, cnt_ns, cnt_total,
                                           tile_counter, tiles, sel_tp, sel_j);
    fill_kernel<<<F4_TOTAL / 256, 256, 0, stream>>>(out, W3, b2, cnt_total);
    main_kernel<<<1024, 256, 0, stream>>>(x, Bb, tile_counter, tiles, cnt_ns,
                                          sel_tp, sel_j, K2, W2, W3, out);
}

// Round 4
// 443.056 us; speedup vs baseline: 1.5575x; 1.5575x over previous
//
#include <hip/hip_runtime.h>

// Problem constants
#define N_    8
#define TP_   2048
#define E_    4096
#define S_    8
#define C_    64
#define T_    16384      // TP_*S_
#define TS_   131072     // T_*S_
#define OUTW  17         // V+1
#define OUT_ELEMS 17825792  // N_*TS_*OUTW
#define F4_PER_N 557056     // 16384 rows * 34 float4 per row
#define F4_TOTAL 4456448    // OUT_ELEMS/4

typedef __attribute__((ext_vector_type(8))) short short8;
typedef __attribute__((ext_vector_type(4))) float float4v;

static __device__ __forceinline__ unsigned short f2bf(float f) {
    unsigned int u = __builtin_bit_cast(unsigned int, f);
    u += 0x7FFFu + ((u >> 16) & 1u);   // round-to-nearest-even
    return (unsigned short)(u >> 16);
}

// ---------------------------------------------------------------------------
// prep: LDS-tiled transpose W1 [4096][512] fp32 -> Bb [512][4096] bf16
//   Bb row index = c*8+s; block (0,0) also computes K2.
// ---------------------------------------------------------------------------
__global__ __launch_bounds__(256) void prep_kernel(
    const float* __restrict__ W1, const float* __restrict__ b1,
    const float* __restrict__ W2, const float* __restrict__ b2,
    unsigned short* __restrict__ Bb, float* __restrict__ K2)
{
    __shared__ float tile[64][65];
    const int tid = threadIdx.x;
    if (blockIdx.x == 0 && blockIdx.y == 0 && tid < 8) {
        int s2 = tid;
        float acc = b2[0];
        for (int c = 0; c < C_; ++c) acc += b1[c] * W2[c * S_ + s2];
        K2[s2] = acc;
    }
    const int e0  = blockIdx.x * 64;   // 64 e-tiles
    const int cs0 = blockIdx.y * 64;   // 8 cs-tiles
    {
        int rr = tid >> 2;        // e row 0..63
        int c4 = tid & 3;
        for (int i = 0; i < 4; ++i) {
            int f4 = c4 + i * 4;  // 0..15
            float4 v = *(const float4*)&W1[(size_t)(e0 + rr) * 512 + cs0 + f4 * 4];
            tile[f4 * 4 + 0][rr] = v.x;
            tile[f4 * 4 + 1][rr] = v.y;
            tile[f4 * 4 + 2][rr] = v.z;
            tile[f4 * 4 + 3][rr] = v.w;
        }
    }
    __syncthreads();
    {
        int cs  = tid >> 2;       // 0..63
        int seg = tid & 3;        // 16 shorts each
        for (int h = 0; h < 2; ++h) {
            short8 o;
#pragma unroll
            for (int j = 0; j < 8; ++j)
                o[j] = (short)f2bf(tile[cs][seg * 16 + h * 8 + j]);
            *(short8*)&Bb[(size_t)(cs0 + cs) * E_ + e0 + seg * 16 + h * 8] = o;
        }
    }
}

// ---------------------------------------------------------------------------
// compact: per (n,s) block; int4 value loads; wave-shuffle scan; 64-ary
// argmax search; builds gathered row lists + global tile work-list.
// ---------------------------------------------------------------------------
__global__ __launch_bounds__(256) void compact_kernel(
    const int* __restrict__ value, const int* __restrict__ depth,
    int* __restrict__ cnt_ns, int* __restrict__ cnt_total,
    int* __restrict__ tile_counter, int* __restrict__ tiles,
    int* __restrict__ sel_tp, int* __restrict__ sel_j)
{
    const int g = blockIdx.x;          // n*8 + s
    const int n = g >> 3;
    const int s = g & 7;
    const int tid  = threadIdx.x;
    const int lane = tid & 63;
    const int wv   = tid >> 6;

    __shared__ int idx_sh;
    __shared__ unsigned int wsum[4];

    const int* d = depth + (size_t)n * T_;
    if (tid < 64) {                    // wave 0: 64-ary search, 3 rounds
        int maxv = d[T_ - 1];
        int lower = 0, upper = T_ - 1;
        for (int rnd = 0; rnd < 3; ++rnd) {
            int span = upper - lower;
            int step = (span + 63) >> 6;
            if (step < 1) step = 1;
            int p = lower + lane * step;
            if (p > upper) p = upper;
            unsigned long long b = __ballot(d[p] == maxv);
            int f = __ffsll((long long)b) - 1;   // ballot never 0: d[upper]==maxv
            int nu = lower + f * step; if (nu > upper) nu = upper;
            int nl = (f == 0) ? lower : lower + (f - 1) * step + 1;
            if (nl > nu) nl = nu;
            lower = nl; upper = nu;
        }
        if (lane == 0) idx_sh = lower;
    }
    __syncthreads();
    const int idx = idx_sh;
    const int4* val4 = (const int4*)(value + (size_t)n * T_);

    const int b4 = tid * 16;           // int4 base; covers t in [tid*64, tid*64+64)
    unsigned int packed = 0;           // (any-count << 16) | s-residue count
    for (int i = 0; i < 16; ++i) {
        int4 v = val4[b4 + i];
        int t = (b4 + i) * 4;
        if (t + 0 < idx && v.x == 2) { packed += 0x10000u; if (((t + 0) & 7) == s) packed += 1u; }
        if (t + 1 < idx && v.y == 2) { packed += 0x10000u; if (((t + 1) & 7) == s) packed += 1u; }
        if (t + 2 < idx && v.z == 2) { packed += 0x10000u; if (((t + 2) & 7) == s) packed += 1u; }
        if (t + 3 < idx && v.w == 2) { packed += 0x10000u; if (((t + 3) & 7) == s) packed += 1u; }
    }
    unsigned int inc = packed;
#pragma unroll
    for (int off = 1; off < 64; off <<= 1) {
        unsigned int u = __shfl_up((int)inc, off, 64);
        if (lane >= off) inc += u;
    }
    if (lane == 63) wsum[wv] = inc;
    __syncthreads();
    unsigned int woff = 0;
    for (int ww = 0; ww < wv; ++ww) woff += wsum[ww];
    unsigned int excl = woff + inc - packed;
    int any_rank = (int)(excl >> 16);
    int s_rank   = (int)(excl & 0xFFFFu);
    for (int i = 0; i < 16; ++i) {
        int4 v = val4[b4 + i];
        int vv[4] = { v.x, v.y, v.z, v.w };
        int t = (b4 + i) * 4;
#pragma unroll
        for (int e = 0; e < 4; ++e) {
            int tt = t + e;
            if (tt < idx && vv[e] == 2) {
                if ((tt & 7) == s) {
                    sel_tp[g * 2048 + s_rank] = tt >> 3;
                    sel_j [g * 2048 + s_rank] = any_rank;
                    ++s_rank;
                }
                ++any_rank;
            }
        }
    }
    if (tid == 255) {
        unsigned int tot = woff + inc;
        int cnt = (int)(tot & 0xFFFFu);
        cnt_ns[g] = cnt;
        if (s == 0) cnt_total[n] = (int)(tot >> 16);
        int ntl = (cnt + 63) >> 6;
        int base = atomicAdd(tile_counter, ntl);
        for (int i = 0; i < ntl; ++i) tiles[base + i] = (g << 8) | i;
    }
}

// ---------------------------------------------------------------------------
// fill: vectorized b2*W3 pattern; skips rows j < cnt_total[n] (main overwrites)
// ---------------------------------------------------------------------------
__global__ __launch_bounds__(256) void fill_kernel(
    float* __restrict__ out, const float* __restrict__ W3,
    const float* __restrict__ b2, const int* __restrict__ cnt_total)
{
    __shared__ float pat[136];
    const int tid = threadIdx.x;
    if (tid < 136) pat[tid] = b2[0] * W3[tid % OUTW];
    __syncthreads();
    int i4 = blockIdx.x * 256 + tid;          // < F4_TOTAL exactly
    int n   = i4 / F4_PER_N;
    int rem = i4 - n * F4_PER_N;
    int j   = rem / 34;                       // output row within sample
    if (j >= cnt_total[n]) {
        int o = (rem - j * 34) * 4;
        float4 v = { pat[o], pat[o + 1], pat[o + 2], pat[o + 3] };
        *(float4*)&out[(size_t)i4 * 4] = v;
    }
}

// ---------------------------------------------------------------------------
// main: work-list driven gathered bf16 MFMA GEMM (64 rows x 64 ch, K=4096).
// K-loop unrolled x2: buffer parity is COMPILE-TIME in each phase, so the
// 2-deep register prefetch sets (Af0/Bf0, Af1/Bf1) stay in VGPRs — the
// round-3 dynamic-index version spilled them to scratch (754 MB WRITE_SIZE).
// One barrier per phase; fused conv2/linear epilogue, coalesced f4 writes.
// ---------------------------------------------------------------------------
__global__ __launch_bounds__(256) void main_kernel(
    const float* __restrict__ x, const unsigned short* __restrict__ Bb,
    const int* __restrict__ tile_counter, const int* __restrict__ tiles,
    const int* __restrict__ cnt_ns, const int* __restrict__ sel_tp,
    const int* __restrict__ sel_j, const float* __restrict__ K2,
    const float* __restrict__ W2, const float* __restrict__ W3,
    float* __restrict__ out)
{
    __shared__ __align__(16) char arena[36864];  // bufA[2]+bufB[2] ∪ (Cl + y2s)
    unsigned short (*bufA)[64][72] = (unsigned short (*)[64][72])arena;
    unsigned short (*bufB)[64][72] = (unsigned short (*)[64][72])(arena + 18432);
    float (*Cl)[68] = (float (*)[68])arena;           // 64x68 fp32 = 17408 B
    float (*y2s)[8] = (float (*)[8])(arena + 17408);  // 64x8 fp32 = 2048 B
    __shared__ int tp_l[64], j_l[64];
    __shared__ float W2s[C_ * S_];
    __shared__ float W3s[OUTW];
    __shared__ float K2s[S_];

    const int tid = threadIdx.x;
    for (int i = tid; i < C_ * S_; i += 256) W2s[i] = W2[i];
    if (tid < OUTW) W3s[tid] = W3[tid];
    if (tid < S_)   K2s[tid] = K2[tid];

    const int ntile = *tile_counter;

    const int lane = tid & 63;
    const int w    = tid >> 6;        // wave id: A rows [w*16, w*16+16)
    const int m    = lane & 15;
    const int q    = lane >> 4;
    const int r    = tid >> 4;        // staging row 0..15
    const int kq   = (tid & 15) << 2; // staging k-offset 0..60

    for (int ti = blockIdx.x; ti < ntile; ti += gridDim.x) {
        const int ent = tiles[ti];
        const int g = ent >> 8;
        const int n = g >> 3;
        const int s = g & 7;
        const int m0 = (ent & 255) * 64;
        const int rows = min(64, cnt_ns[g] - m0);

        __syncthreads();   // previous tile's epilogue fully done (LDS reuse)
        if (tid < 64) {
            int tp = 0, j = 0;
            if (tid < rows) {
                tp = sel_tp[g * 2048 + m0 + tid];
                j  = sel_j [g * 2048 + m0 + tid];
            }
            tp_l[tid] = tp;
            j_l[tid]  = j;
        }
        __syncthreads();

        const float* ap[4];
        const unsigned short* bp[4];
#pragma unroll
        for (int l = 0; l < 4; ++l) {
            int row = r + (l << 4);
            ap[l] = x + ((size_t)n * TP_ + tp_l[row]) * E_ + kq;
            bp[l] = Bb + ((size_t)(row * 8 + s)) * E_ + kq;   // Bb row = c*8+s
        }

        // 2-deep register prefetch, named sets (no dynamic indexing!)
        float4  Af0[4], Af1[4];
        ushort4 Bf0[4], Bf1[4];
#pragma unroll
        for (int l = 0; l < 4; ++l) {
            Af0[l] = *(const float4*)(ap[l]);
            Bf0[l] = *(const ushort4*)(bp[l]);
            Af1[l] = *(const float4*)(ap[l] + 64);
            Bf1[l] = *(const ushort4*)(bp[l] + 64);
        }

        float4v acc[4];
#pragma unroll
        for (int nt = 0; nt < 4; ++nt) acc[nt] = (float4v){0.f, 0.f, 0.f, 0.f};

#define GEMM_PHASE(P, AF, BF)                                                 \
        {                                                                     \
            _Pragma("unroll")                                                 \
            for (int l = 0; l < 4; ++l) {                                     \
                int row = r + (l << 4);                                       \
                ushort4 av;                                                   \
                av.x = f2bf(AF[l].x); av.y = f2bf(AF[l].y);                   \
                av.z = f2bf(AF[l].z); av.w = f2bf(AF[l].w);                   \
                *(ushort4*)&bufA[P][row][kq] = av;                            \
                *(ushort4*)&bufB[P][row][kq] = BF[l];                         \
            }                                                                 \
            __syncthreads();                                                  \
            if (kb + 2 + P < 64) {                                            \
                const int k0 = (kb + 2 + P) * 64;                             \
                _Pragma("unroll")                                             \
                for (int l = 0; l < 4; ++l) {                                 \
                    AF[l] = *(const float4*)(ap[l] + k0);                     \
                    BF[l] = *(const ushort4*)(bp[l] + k0);                    \
                }                                                             \
            }                                                                 \
            _Pragma("unroll")                                                 \
            for (int ks = 0; ks < 2; ++ks) {                                  \
                short8 a = *(const short8*)&bufA[P][w * 16 + m][ks * 32 + q * 8]; \
                _Pragma("unroll")                                             \
                for (int nt = 0; nt < 4; ++nt) {                              \
                    short8 b = *(const short8*)&bufB[P][nt * 16 + m][ks * 32 + q * 8]; \
                    acc[nt] = __builtin_amdgcn_mfma_f32_16x16x32_bf16(a, b, acc[nt], 0, 0, 0); \
                }                                                             \
            }                                                                 \
        }

        for (int kb = 0; kb < 64; kb += 2) {
            GEMM_PHASE(0, Af0, Bf0)
            GEMM_PHASE(1, Af1, Bf1)
        }
#undef GEMM_PHASE

        __syncthreads();   // all LDS reads done before Cl alias write

        // D layout: row = q*4+reg, col = lane&15 (m89-verified)
#pragma unroll
        for (int nt = 0; nt < 4; ++nt)
#pragma unroll
            for (int rr = 0; rr < 4; ++rr)
                Cl[w * 16 + q * 4 + rr][nt * 16 + m] = acc[nt][rr];
        __syncthreads();

        // y2[row][s2] = K2[s2] + sum_c C[row][c]*W2[c,s2]
        for (int task = tid; task < 512; task += 256) {
            int row = task >> 3;
            int s2  = task & 7;
            float y2 = K2s[s2];
#pragma unroll
            for (int c = 0; c < C_; ++c) y2 += Cl[row][c] * W2s[c * S_ + s2];
            y2s[row][s2] = y2;
        }
        __syncthreads();

        // coalesced writes: each output row is 136 consecutive floats = 34 f4
        for (int task = tid; task < 64 * 34; task += 256) {
            int row = task / 34;
            int f   = task - row * 34;
            if (row < rows) {
                float4 v;
                float* vp = (float*)&v;
#pragma unroll
                for (int e = 0; e < 4; ++e) {
                    int idx = f * 4 + e;
                    int s2  = (idx * 241) >> 12;   // idx/17 for idx<136
                    int vi  = idx - s2 * OUTW;
                    vp[e] = y2s[row][s2] * W3s[vi];
                }
                *(float4*)&out[((size_t)n * TS_ + (size_t)j_l[row] * S_) * OUTW + f * 4] = v;
            }
        }
    }
}

// ---------------------------------------------------------------------------
extern "C" void kernel_launch(void* const* d_in, const int* in_sizes, int n_in,
                              void* d_out, int out_size, void* d_ws, size_t ws_size,
                              hipStream_t stream) {
    const float* x     = (const float*)d_in[0];
    const int*   value = (const int*)d_in[1];
    const int*   depth = (const int*)d_in[2];
    // d_in[3] = pos (unused by reference)
    const float* W1    = (const float*)d_in[4];
    const float* b1    = (const float*)d_in[5];
    const float* W2    = (const float*)d_in[6];
    const float* b2    = (const float*)d_in[7];
    const float* W3    = (const float*)d_in[8];
    float* out = (float*)d_out;

    // workspace layout (~5.25 MB)
    unsigned short* Bb = (unsigned short*)d_ws;            // 512*4096 bf16 = 4 MB
    float* K2          = (float*)(Bb + 512 * 4096);        // 8
    int* tile_counter  = (int*)(K2 + 8);                   // 1
    int* cnt_ns        = tile_counter + 1;                 // 64
    int* cnt_total     = cnt_ns + 64;                      // 8
    int* tiles         = cnt_total + 8;                    // 2048 max
    int* sel_tp        = tiles + 2048;                     // 64*2048
    int* sel_j         = sel_tp + 64 * 2048;               // 64*2048

    hipMemsetAsync(tile_counter, 0, sizeof(int), stream);

    dim3 pgrid(64, 8);
    prep_kernel<<<pgrid, 256, 0, stream>>>(W1, b1, W2, b2, Bb, K2);
    compact_kernel<<<64, 256, 0, stream>>>(value, depth, cnt_ns, cnt_total,
                                           tile_counter, tiles, sel_tp, sel_j);
    fill_kernel<<<F4_TOTAL / 256, 256, 0, stream>>>(out, W3, b2, cnt_total);
    main_kernel<<<512, 256, 0, stream>>>(x, Bb, tile_counter, tiles, cnt_ns,
                                         sel_tp, sel_j, K2, W2, W3, out);
}